// Round 11
// baseline (178.043 us; speedup 1.0000x reference)
//
#include <hip/hip_runtime.h>

// GCN 2-layer + linear head on MI355X.
// R10 post-mortem: agg is VALU-bound (65% VALUBusy, mem comfortable).
// Per-node fixed cost (24-shfl butterfly reduce + 16-wide epilogue) dominates
// at mean degree 12.5. R11: recursive-halving reduce (7 shfl, each lane ends
// owning ONE feature -> scalar epilogue/store), v_pk_add_f32 unpack-adds,
// CHUNK 2048 for sort-grid balance.

typedef float v2f __attribute__((ext_vector_type(2)));

constexpr int NB_SHIFT = 8;                 // 256 nodes per bucket
constexpr int BUCK_NODES = 1 << NB_SHIFT;
constexpr int CAP = 5120;                   // slab cap (mean padded ~4096 + 15 sigma)
constexpr int CHUNK = 2048;                 // edges per sort block
constexpr int STPB = 512;
// assumes nbuck <= 512, src < 2^17, padded bucket size <= CAP

// ---- init: slab cursors + dummy bf16 row (replaces hipMemsetAsync) -----
__global__ __launch_bounds__(512) void k_init(int* __restrict__ gcur, int nbuck,
                                              unsigned short* __restrict__ dummyRow) {
    int t = threadIdx.x;
    if (t < nbuck) gcur[t] = 0;
    if (t < 64) dummyRow[t] = 0;
}

// ---- fused: chunk histogram -> slab reserve -> LDS sort -> dense flush -
__global__ __launch_bounds__(STPB) void k_bsort(const int* __restrict__ src,
                                                const int* __restrict__ dst, int E, int nbuck,
                                                int* __restrict__ gcur,
                                                unsigned* __restrict__ packed) {
    __shared__ int shStart[512];
    __shared__ int shCur[512];
    __shared__ int shOff[512];
    __shared__ unsigned stage[CHUNK];
    __shared__ unsigned short sbkt[CHUNK];
    const int tid = threadIdx.x;
    const int base = blockIdx.x * CHUNK;
    const int end = min(base + CHUNK, E);
    // pass A: count buckets in this chunk (LDS atomics)
    shCur[tid] = 0;
    __syncthreads();
    for (int e = base + tid; e < end; e += STPB)
        atomicAdd(&shCur[dst[e] >> NB_SHIFT], 1);
    __syncthreads();
    int v = shCur[tid];
    shStart[tid] = v;
    __syncthreads();
    for (int s = 1; s < 512; s <<= 1) {      // inclusive Hillis-Steele
        int a = (tid >= s) ? shStart[tid - s] : 0;
        __syncthreads();
        shStart[tid] += a;
        __syncthreads();
    }
    int exc = shStart[tid] - v;
    shStart[tid] = exc;
    shCur[tid] = exc;
    // reserve this chunk's span in bucket slabs (one global atomic each)
    if (tid < nbuck) shOff[tid] = tid * CAP + ((v > 0) ? atomicAdd(&gcur[tid], v) : 0);
    __syncthreads();
    // pass B: permute chunk into LDS, bucket-major
    for (int e = base + tid; e < end; e += STPB) {
        int s = src[e];
        int d = dst[e];
        int b = d >> NB_SHIFT;
        int slot = atomicAdd(&shCur[b], 1);
        stage[slot] = ((unsigned)(d & (BUCK_NODES - 1)) << 17) | (unsigned)s;
        sbkt[slot] = (unsigned short)b;
    }
    __syncthreads();
    // pass C: linear flush, same-bucket runs land contiguously
    int cnt = end - base;
    for (int i = tid; i < cnt; i += STPB) {
        int b = sbkt[i];
        packed[shOff[b] + (i - shStart[b])] = stage[i];
    }
}

// ---- per-bucket counting sort by dstLocal -> csr slab (x8-padded rows),
//      rowinfo=(start, paddedCount), dinv ------------------------------
__global__ __launch_bounds__(512) void k_csr(const unsigned* __restrict__ packed,
                                             const int* __restrict__ gcur, int n,
                                             int* __restrict__ csr, int2* __restrict__ rowinfo,
                                             float* __restrict__ dinv) {
    __shared__ int cnt[BUCK_NODES];
    __shared__ int scn[BUCK_NODES];
    __shared__ int cur[BUCK_NODES];
    const int tid = threadIdx.x;
    const int e0 = blockIdx.x * CAP;
    const int e1 = e0 + gcur[blockIdx.x];     // slab base + size
    if (tid < BUCK_NODES) cnt[tid] = 0;
    __syncthreads();
    for (int e = e0 + tid; e < e1; e += 512)
        atomicAdd(&cnt[packed[e] >> 17], 1);
    __syncthreads();
    int v = (tid < BUCK_NODES) ? cnt[tid] : 0;
    int pad = (v + 7) & ~7;                   // pad each node's list to x8
    if (tid < BUCK_NODES) scn[tid] = pad;
    __syncthreads();
    for (int s = 1; s < BUCK_NODES; s <<= 1) {   // inclusive Hillis-Steele
        int add = (tid >= s && tid < BUCK_NODES) ? scn[tid - s] : 0;
        __syncthreads();
        if (tid < BUCK_NODES) scn[tid] += add;
        __syncthreads();
    }
    int start = 0;
    if (tid < BUCK_NODES) {
        start = e0 + scn[tid] - pad;
        cur[tid] = start;
        int node = blockIdx.x * BUCK_NODES + tid;
        if (node < n) {
            rowinfo[node] = make_int2(start, pad);
            dinv[node] = rsqrtf(1.0f + (float)v);
        }
    }
    __syncthreads();
    for (int e = e0 + tid; e < e1; e += 512) {
        unsigned p = packed[e];
        int pos = atomicAdd(&cur[p >> 17], 1);   // LDS cursor
        csr[pos] = (int)(p & 0x1FFFFu);          // dense slab window, L2-hot
    }
    __syncthreads();
    // pad tail with dummy node index n (zero bf16 row in g)
    if (tid < BUCK_NODES) {
        for (int p = v; p < pad; ++p) csr[start + p] = n;
    }
}

// ---- GEMM: gBf[i][f] = bf16((sum_k A[i][k] * W[k][f]) * dinv[i]) -------
__global__ __launch_bounds__(256) void k_gemm64bf(const float* __restrict__ A,
                                                  const float* __restrict__ W,
                                                  const float* __restrict__ dinv,
                                                  unsigned short* __restrict__ out,
                                                  int n) {
    const int lane = threadIdx.x & 63;
    const int wave = threadIdx.x >> 6;
    float wcol[64];
#pragma unroll
    for (int k = 0; k < 64; ++k) wcol[k] = W[k * 64 + lane];
    int base = blockIdx.x * 64;
    for (int r = wave; r < 64; r += 4) {
        int row = base + r;
        if (row >= n) break;
        float a = A[(size_t)row * 64 + lane];
        float acc = 0.0f;
#pragma unroll
        for (int k = 0; k < 64; ++k) {
            float ak = __uint_as_float(__builtin_amdgcn_readlane(__float_as_uint(a), k));
            acc = fmaf(ak, wcol[k], acc);
        }
        float val = acc * dinv[row];
        unsigned u = __float_as_uint(val);
        u = (u + 0x7FFFu + ((u >> 16) & 1u)) >> 16;   // RNE to bf16
        out[(size_t)row * 64 + lane] = (unsigned short)u;
    }
}

__device__ __forceinline__ v2f bf2(unsigned u) {
    v2f r;
    r.x = __uint_as_float(u << 16);
    r.y = __uint_as_float(u & 0xFFFF0000u);
    return r;
}

// ---- Aggregate: one wave per node; bf16 rows, 8 edges per dwordx4 ------
// lane = 8*grp + q; grp handles edge e+8r+grp, q the 16B row chunk
// (features 8q..8q+7). Recursive-halving reduce: after 7 shfl each lane
// owns ONE feature f = 8q + 4*g0 + 2*g1 + g2 -> scalar epilogue & store.
template <bool LAST>
__global__ __launch_bounds__(256) void k_aggregate(
    const uint4* __restrict__ g4, const unsigned short* __restrict__ gRow,
    const int2* __restrict__ rowinfo, const int* __restrict__ csr,
    const float* __restrict__ dinv, const float* __restrict__ bias,
    const float* __restrict__ Wo, const float* __restrict__ bo,
    float* __restrict__ outRow, float* __restrict__ outHead, int n) {
    int t = blockIdx.x * blockDim.x + threadIdx.x;
    int node = t >> 6;
    int lane = t & 63;
    if (node >= n) return;
    const int grp = lane >> 3;                // 0..7
    const int q = lane & 7;                   // 0..7
    int2 ri = rowinfo[node];
    const int e = ri.x;
    const int rounds = ri.y >> 3;
    v2f a0v = {0.f, 0.f}, a1v = {0.f, 0.f}, a2v = {0.f, 0.f}, a3v = {0.f, 0.f};
    int r = 0;
    for (; r + 2 <= rounds; r += 2) {         // 16 edge-rows in flight / wave
        int i0 = csr[e + r * 8 + grp];
        int i1 = csr[e + r * 8 + 8 + grp];
        uint4 x0 = g4[(size_t)i0 * 8 + q];
        uint4 x1 = g4[(size_t)i1 * 8 + q];
        a0v += bf2(x0.x); a1v += bf2(x0.y); a2v += bf2(x0.z); a3v += bf2(x0.w);
        a0v += bf2(x1.x); a1v += bf2(x1.y); a2v += bf2(x1.z); a3v += bf2(x1.w);
    }
    if (r < rounds) {
        int i0 = csr[e + r * 8 + grp];
        uint4 x0 = g4[(size_t)i0 * 8 + q];
        a0v += bf2(x0.x); a1v += bf2(x0.y); a2v += bf2(x0.z); a3v += bf2(x0.w);
    }
    // flat acc[k] = feature 8q+k
    float f0 = a0v.x, f1 = a0v.y, f2 = a1v.x, f3 = a1v.y;
    float f4 = a2v.x, f5 = a2v.y, f6 = a3v.x, f7 = a3v.y;
    // recursive-halving reduce over grp bits: 8 -> 1 features per lane
    bool ge0 = (grp & 1) == 0;                // round 1 (mask 8): keep 0..3 / 4..7
    float k0 = ge0 ? f0 : f4, s0 = ge0 ? f4 : f0;
    float k1 = ge0 ? f1 : f5, s1 = ge0 ? f5 : f1;
    float k2 = ge0 ? f2 : f6, s2 = ge0 ? f6 : f2;
    float k3 = ge0 ? f3 : f7, s3 = ge0 ? f7 : f3;
    k0 += __shfl_xor(s0, 8, 64);
    k1 += __shfl_xor(s1, 8, 64);
    k2 += __shfl_xor(s2, 8, 64);
    k3 += __shfl_xor(s3, 8, 64);
    bool ge1 = (grp & 2) == 0;                // round 2 (mask 16): keep 0,1 / 2,3
    float m0 = ge1 ? k0 : k2, t0 = ge1 ? k2 : k0;
    float m1 = ge1 ? k1 : k3, t1 = ge1 ? k3 : k1;
    m0 += __shfl_xor(t0, 16, 64);
    m1 += __shfl_xor(t1, 16, 64);
    bool ge2 = (grp & 4) == 0;                // round 3 (mask 32): keep 0 / 1
    float kf = ge2 ? m0 : m1, sf = ge2 ? m1 : m0;
    kf += __shfl_xor(sf, 32, 64);
    // the one feature this lane owns
    int f = 8 * q + 4 * (grp & 1) + 2 * ((grp >> 1) & 1) + ((grp >> 2) & 1);
    // self-loop term (bf16 scalar)
    unsigned su = gRow[(size_t)node * 64 + f];
    kf += __uint_as_float(su << 16);
    float vv = fmaxf(fmaf(dinv[node], kf, bias[f]), 0.f);
    if constexpr (LAST) {
        float p = vv * Wo[f];
#pragma unroll
        for (int m = 1; m < 64; m <<= 1) p += __shfl_xor(p, m, 64);
        if (lane == 0) outHead[node] = p + bo[0];
    } else {
        outRow[(size_t)node * 64 + f] = vv;
    }
}

extern "C" void kernel_launch(void* const* d_in, const int* in_sizes, int n_in,
                              void* d_out, int out_size, void* d_ws, size_t ws_size,
                              hipStream_t stream) {
    const float* x  = (const float*)d_in[0];
    const int*   ei = (const int*)d_in[1];
    const float* W1 = (const float*)d_in[2];
    const float* b1 = (const float*)d_in[3];
    const float* W2 = (const float*)d_in[4];
    const float* b2 = (const float*)d_in[5];
    const float* Wo = (const float*)d_in[6];
    const float* bo = (const float*)d_in[7];
    float* out = (float*)d_out;

    const int n = in_sizes[0] / 64;
    const int E = in_sizes[1] / 2;
    const int* src = ei;
    const int* dst = ei + E;

    const int nbuck = (n + BUCK_NODES - 1) >> NB_SHIFT;      // 391
    const int nchunks = (E + CHUNK - 1) / CHUNK;             // 611

    char* ws = (char*)d_ws;
    size_t off = 0;
    auto alloc = [&](size_t bytes) -> void* {
        void* p = ws + off;
        off += (bytes + 255) & ~(size_t)255;
        return p;
    };
    const size_t slabBytes = (size_t)nbuck * CAP * 4;        // 8.0 MB
    const size_t hBytes    = (size_t)n * 64 * 4;             // 25.6 MB (fp32 h1)
    const size_t gBytes    = (size_t)(n + 1) * 64 * 2;       // 12.8 MB (bf16 g + dummy)
    float*          dinv    = (float*)alloc((size_t)n * 4);
    int*            gcur    = (int*)alloc((size_t)nbuck * 4);
    int2*           rowinfo = (int2*)alloc((size_t)n * 8);
    int*            csr     = (int*)alloc(slabBytes);
    char*           regionA = (char*)alloc(hBytes > slabBytes ? hBytes : slabBytes);
    unsigned short* gBf     = (unsigned short*)alloc(gBytes);
    unsigned* packed = (unsigned*)regionA;   // dead after k_csr
    float*    bufH   = (float*)regionA;      // h1 (fp32), written from agg1 on

    // ---- init (slab cursors + dummy bf16 row) ----
    k_init<<<1, 512, 0, stream>>>(gcur, nbuck, gBf + (size_t)n * 64);

    // ---- slab counting sort -> dst-sorted csr slabs + rowinfo + dinv ----
    k_bsort<<<nchunks, STPB, 0, stream>>>(src, dst, E, nbuck, gcur, packed);
    k_csr<<<nbuck, 512, 0, stream>>>(packed, gcur, n, csr, rowinfo, dinv);

    const int gemmGrid = (n + 63) / 64;
    const int nodeGrid = (n + 3) / 4;        // one wave per node, 4 waves/block

    // ---- layer 1 ----
    k_gemm64bf<<<gemmGrid, 256, 0, stream>>>(x, W1, dinv, gBf, n);
    k_aggregate<false><<<nodeGrid, 256, 0, stream>>>((const uint4*)gBf, gBf, rowinfo, csr,
                                                     dinv, b1, nullptr, nullptr,
                                                     bufH, nullptr, n);
    // ---- layer 2 (head fused into epilogue) ----
    k_gemm64bf<<<gemmGrid, 256, 0, stream>>>(bufH, W2, dinv, gBf, n);
    k_aggregate<true><<<nodeGrid, 256, 0, stream>>>((const uint4*)gBf, gBf, rowinfo, csr,
                                                    dinv, b2, Wo, bo,
                                                    nullptr, out, n);
}

// Round 12
// 158.058 us; speedup vs baseline: 1.1264x; 1.1264x over previous
//
#include <hip/hip_runtime.h>

// GCN 2-layer + linear head on MI355X.
// R11 post-mortem: halving-reduce helped agg slightly but CHUNK 2048 doubled
// bsort fixed cost -> net neutral. Per-wave model: ~60% of agg time is
// per-node FIXED cost paid 100k times.
// R12: TWO nodes per wave (32 lanes/node = 4 edge-grps x 8 quad-lanes):
// halves wave count -> halves fixed cost/node; inner gather rate unchanged.
// Edge lists pad to x4; reduce = 2 halving rounds (6 shfl); float2 epilogue.
// CHUNK back to 4096.

typedef float v2f __attribute__((ext_vector_type(2)));

constexpr int NB_SHIFT = 8;                 // 256 nodes per bucket
constexpr int BUCK_NODES = 1 << NB_SHIFT;
constexpr int CAP = 5120;                   // slab cap (mean ~3600 padded, huge margin)
constexpr int CHUNK = 4096;                 // edges per sort block
constexpr int STPB = 512;
// assumes nbuck <= 512, src < 2^17, padded bucket size <= CAP

// ---- init: slab cursors + dummy bf16 row (replaces hipMemsetAsync) -----
__global__ __launch_bounds__(512) void k_init(int* __restrict__ gcur, int nbuck,
                                              unsigned short* __restrict__ dummyRow) {
    int t = threadIdx.x;
    if (t < nbuck) gcur[t] = 0;
    if (t < 64) dummyRow[t] = 0;
}

// ---- fused: chunk histogram -> slab reserve -> LDS sort -> dense flush -
__global__ __launch_bounds__(STPB) void k_bsort(const int* __restrict__ src,
                                                const int* __restrict__ dst, int E, int nbuck,
                                                int* __restrict__ gcur,
                                                unsigned* __restrict__ packed) {
    __shared__ int shStart[512];
    __shared__ int shCur[512];
    __shared__ int shOff[512];
    __shared__ unsigned stage[CHUNK];
    __shared__ unsigned short sbkt[CHUNK];
    const int tid = threadIdx.x;
    const int base = blockIdx.x * CHUNK;
    const int end = min(base + CHUNK, E);
    // pass A: count buckets in this chunk (LDS atomics)
    shCur[tid] = 0;
    __syncthreads();
    for (int e = base + tid; e < end; e += STPB)
        atomicAdd(&shCur[dst[e] >> NB_SHIFT], 1);
    __syncthreads();
    int v = shCur[tid];
    shStart[tid] = v;
    __syncthreads();
    for (int s = 1; s < 512; s <<= 1) {      // inclusive Hillis-Steele
        int a = (tid >= s) ? shStart[tid - s] : 0;
        __syncthreads();
        shStart[tid] += a;
        __syncthreads();
    }
    int exc = shStart[tid] - v;
    shStart[tid] = exc;
    shCur[tid] = exc;
    // reserve this chunk's span in bucket slabs (one global atomic each)
    if (tid < nbuck) shOff[tid] = tid * CAP + ((v > 0) ? atomicAdd(&gcur[tid], v) : 0);
    __syncthreads();
    // pass B: permute chunk into LDS, bucket-major
    for (int e = base + tid; e < end; e += STPB) {
        int s = src[e];
        int d = dst[e];
        int b = d >> NB_SHIFT;
        int slot = atomicAdd(&shCur[b], 1);
        stage[slot] = ((unsigned)(d & (BUCK_NODES - 1)) << 17) | (unsigned)s;
        sbkt[slot] = (unsigned short)b;
    }
    __syncthreads();
    // pass C: linear flush, same-bucket runs land contiguously
    int cnt = end - base;
    for (int i = tid; i < cnt; i += STPB) {
        int b = sbkt[i];
        packed[shOff[b] + (i - shStart[b])] = stage[i];
    }
}

// ---- per-bucket counting sort by dstLocal -> csr slab (x4-padded rows),
//      rowinfo=(start, paddedCount), dinv ------------------------------
__global__ __launch_bounds__(512) void k_csr(const unsigned* __restrict__ packed,
                                             const int* __restrict__ gcur, int n,
                                             int* __restrict__ csr, int2* __restrict__ rowinfo,
                                             float* __restrict__ dinv) {
    __shared__ int cnt[BUCK_NODES];
    __shared__ int scn[BUCK_NODES];
    __shared__ int cur[BUCK_NODES];
    const int tid = threadIdx.x;
    const int e0 = blockIdx.x * CAP;
    const int e1 = e0 + gcur[blockIdx.x];     // slab base + size
    if (tid < BUCK_NODES) cnt[tid] = 0;
    __syncthreads();
    for (int e = e0 + tid; e < e1; e += 512)
        atomicAdd(&cnt[packed[e] >> 17], 1);
    __syncthreads();
    int v = (tid < BUCK_NODES) ? cnt[tid] : 0;
    int pad = (v + 3) & ~3;                   // pad each node's list to x4
    if (tid < BUCK_NODES) scn[tid] = pad;
    __syncthreads();
    for (int s = 1; s < BUCK_NODES; s <<= 1) {   // inclusive Hillis-Steele
        int add = (tid >= s && tid < BUCK_NODES) ? scn[tid - s] : 0;
        __syncthreads();
        if (tid < BUCK_NODES) scn[tid] += add;
        __syncthreads();
    }
    int start = 0;
    if (tid < BUCK_NODES) {
        start = e0 + scn[tid] - pad;
        cur[tid] = start;
        int node = blockIdx.x * BUCK_NODES + tid;
        if (node < n) {
            rowinfo[node] = make_int2(start, pad);
            dinv[node] = rsqrtf(1.0f + (float)v);
        }
    }
    __syncthreads();
    for (int e = e0 + tid; e < e1; e += 512) {
        unsigned p = packed[e];
        int pos = atomicAdd(&cur[p >> 17], 1);   // LDS cursor
        csr[pos] = (int)(p & 0x1FFFFu);          // dense slab window, L2-hot
    }
    __syncthreads();
    // pad tail with dummy node index n (zero bf16 row in g)
    if (tid < BUCK_NODES) {
        for (int p = v; p < pad; ++p) csr[start + p] = n;
    }
}

// ---- GEMM: gBf[i][f] = bf16((sum_k A[i][k] * W[k][f]) * dinv[i]) -------
__global__ __launch_bounds__(256) void k_gemm64bf(const float* __restrict__ A,
                                                  const float* __restrict__ W,
                                                  const float* __restrict__ dinv,
                                                  unsigned short* __restrict__ out,
                                                  int n) {
    const int lane = threadIdx.x & 63;
    const int wave = threadIdx.x >> 6;
    float wcol[64];
#pragma unroll
    for (int k = 0; k < 64; ++k) wcol[k] = W[k * 64 + lane];
    int base = blockIdx.x * 64;
    for (int r = wave; r < 64; r += 4) {
        int row = base + r;
        if (row >= n) break;
        float a = A[(size_t)row * 64 + lane];
        float acc = 0.0f;
#pragma unroll
        for (int k = 0; k < 64; ++k) {
            float ak = __uint_as_float(__builtin_amdgcn_readlane(__float_as_uint(a), k));
            acc = fmaf(ak, wcol[k], acc);
        }
        float val = acc * dinv[row];
        unsigned u = __float_as_uint(val);
        u = (u + 0x7FFFu + ((u >> 16) & 1u)) >> 16;   // RNE to bf16
        out[(size_t)row * 64 + lane] = (unsigned short)u;
    }
}

__device__ __forceinline__ v2f bf2(unsigned u) {
    v2f r;
    r.x = __uint_as_float(u << 16);
    r.y = __uint_as_float(u & 0xFFFF0000u);
    return r;
}

// ---- Aggregate: TWO nodes per wave (32 lanes each); bf16 rows ----------
// lane = 32*h + 8*grp + q. Node half h; grp handles edge e+4r+grp; q the
// 16B row chunk (features 8q..8q+7). Reduce: 2 halving rounds -> each lane
// owns features {base, base+1}, base = 8q+4*g0+2*g1. float2 epilogue.
template <bool LAST>
__global__ __launch_bounds__(256) void k_aggregate(
    const uint4* __restrict__ g4, const unsigned short* __restrict__ gRow,
    const int2* __restrict__ rowinfo, const int* __restrict__ csr,
    const float* __restrict__ dinv, const float* __restrict__ bias,
    const float* __restrict__ Wo, const float* __restrict__ bo,
    float* __restrict__ outRow, float* __restrict__ outHead, int n) {
    int w = (blockIdx.x * blockDim.x + threadIdx.x) >> 6;
    int lane = threadIdx.x & 63;
    const int h = lane >> 5;                  // node half 0/1
    const int grp = (lane >> 3) & 3;          // 0..3
    const int q = lane & 7;                   // 0..7
    int node = 2 * w + h;
    if (node >= n) return;
    int2 ri = rowinfo[node];
    const int e = ri.x;
    const int rnds = ri.y >> 2;
    int rm = max(rnds, __shfl_xor(rnds, 32, 64));   // max over both halves
    v2f a0v = {0.f, 0.f}, a1v = {0.f, 0.f}, a2v = {0.f, 0.f}, a3v = {0.f, 0.f};
    int r = 0;
    for (; r + 2 <= rm; r += 2) {             // 16 edge-rows in flight / wave
        int c0 = csr[e + r * 4 + grp];        // safe over-read, clamped below
        int c1 = csr[e + r * 4 + 4 + grp];
        int i0 = (r < rnds) ? c0 : n;
        int i1 = (r + 1 < rnds) ? c1 : n;
        uint4 x0 = g4[(size_t)i0 * 8 + q];
        uint4 x1 = g4[(size_t)i1 * 8 + q];
        a0v += bf2(x0.x); a1v += bf2(x0.y); a2v += bf2(x0.z); a3v += bf2(x0.w);
        a0v += bf2(x1.x); a1v += bf2(x1.y); a2v += bf2(x1.z); a3v += bf2(x1.w);
    }
    if (r < rm) {
        int c0 = csr[e + r * 4 + grp];
        int i0 = (r < rnds) ? c0 : n;
        uint4 x0 = g4[(size_t)i0 * 8 + q];
        a0v += bf2(x0.x); a1v += bf2(x0.y); a2v += bf2(x0.z); a3v += bf2(x0.w);
    }
    // halving reduce over the 4 grps (features 8q..8q+7 identical per grp)
    bool g0 = (grp & 1) != 0;                 // round 1: mask 8
    v2f keepA = g0 ? a2v : a0v;               // kept base: 8q + 4*g0
    v2f keepB = g0 ? a3v : a1v;
    v2f sendA = g0 ? a0v : a2v;
    v2f sendB = g0 ? a1v : a3v;
    keepA.x += __shfl_xor(sendA.x, 8, 64);
    keepA.y += __shfl_xor(sendA.y, 8, 64);
    keepB.x += __shfl_xor(sendB.x, 8, 64);
    keepB.y += __shfl_xor(sendB.y, 8, 64);
    bool g1 = (grp & 2) != 0;                 // round 2: mask 16
    v2f keep = g1 ? keepB : keepA;            // kept base: 8q + 4*g0 + 2*g1
    v2f send = g1 ? keepA : keepB;
    keep.x += __shfl_xor(send.x, 16, 64);
    keep.y += __shfl_xor(send.y, 16, 64);
    const int base = 8 * q + 4 * (grp & 1) + ((grp & 2) ? 2 : 0);
    // self-loop term (bf16 pair)
    unsigned su = *(const unsigned*)&gRow[(size_t)node * 64 + base];
    keep += bf2(su);
    float dv = dinv[node];
    float2 bb = *(const float2*)&bias[base];
    float ox = fmaxf(fmaf(dv, keep.x, bb.x), 0.f);
    float oy = fmaxf(fmaf(dv, keep.y, bb.y), 0.f);
    if constexpr (LAST) {
        float2 ww = *(const float2*)&Wo[base];
        float p = ox * ww.x + oy * ww.y;
#pragma unroll
        for (int m = 1; m <= 16; m <<= 1) p += __shfl_xor(p, m, 64);
        if ((lane & 31) == 0) outHead[node] = p + bo[0];
    } else {
        float2 o = make_float2(ox, oy);
        *(float2*)&outRow[(size_t)node * 64 + base] = o;
    }
}

extern "C" void kernel_launch(void* const* d_in, const int* in_sizes, int n_in,
                              void* d_out, int out_size, void* d_ws, size_t ws_size,
                              hipStream_t stream) {
    const float* x  = (const float*)d_in[0];
    const int*   ei = (const int*)d_in[1];
    const float* W1 = (const float*)d_in[2];
    const float* b1 = (const float*)d_in[3];
    const float* W2 = (const float*)d_in[4];
    const float* b2 = (const float*)d_in[5];
    const float* Wo = (const float*)d_in[6];
    const float* bo = (const float*)d_in[7];
    float* out = (float*)d_out;

    const int n = in_sizes[0] / 64;
    const int E = in_sizes[1] / 2;
    const int* src = ei;
    const int* dst = ei + E;

    const int nbuck = (n + BUCK_NODES - 1) >> NB_SHIFT;      // 391
    const int nchunks = (E + CHUNK - 1) / CHUNK;             // 306

    char* ws = (char*)d_ws;
    size_t off = 0;
    auto alloc = [&](size_t bytes) -> void* {
        void* p = ws + off;
        off += (bytes + 255) & ~(size_t)255;
        return p;
    };
    const size_t slabBytes = (size_t)nbuck * CAP * 4;        // 8.0 MB
    const size_t hBytes    = (size_t)n * 64 * 4;             // 25.6 MB (fp32 h1)
    const size_t gBytes    = (size_t)(n + 1) * 64 * 2;       // 12.8 MB (bf16 g + dummy)
    float*          dinv    = (float*)alloc((size_t)n * 4);
    int*            gcur    = (int*)alloc((size_t)nbuck * 4);
    int2*           rowinfo = (int2*)alloc((size_t)n * 8);
    int*            csr     = (int*)alloc(slabBytes);
    char*           regionA = (char*)alloc(hBytes > slabBytes ? hBytes : slabBytes);
    unsigned short* gBf     = (unsigned short*)alloc(gBytes);
    unsigned* packed = (unsigned*)regionA;   // dead after k_csr
    float*    bufH   = (float*)regionA;      // h1 (fp32), written from agg1 on

    // ---- init (slab cursors + dummy bf16 row) ----
    k_init<<<1, 512, 0, stream>>>(gcur, nbuck, gBf + (size_t)n * 64);

    // ---- slab counting sort -> dst-sorted csr slabs + rowinfo + dinv ----
    k_bsort<<<nchunks, STPB, 0, stream>>>(src, dst, E, nbuck, gcur, packed);
    k_csr<<<nbuck, 512, 0, stream>>>(packed, gcur, n, csr, rowinfo, dinv);

    const int gemmGrid = (n + 63) / 64;
    const int nodeGrid = (n + 7) / 8;        // 2 nodes/wave, 4 waves/block

    // ---- layer 1 ----
    k_gemm64bf<<<gemmGrid, 256, 0, stream>>>(x, W1, dinv, gBf, n);
    k_aggregate<false><<<nodeGrid, 256, 0, stream>>>((const uint4*)gBf, gBf, rowinfo, csr,
                                                     dinv, b1, nullptr, nullptr,
                                                     bufH, nullptr, n);
    // ---- layer 2 (head fused into epilogue) ----
    k_gemm64bf<<<gemmGrid, 256, 0, stream>>>(bufH, W2, dinv, gBf, n);
    k_aggregate<true><<<nodeGrid, 256, 0, stream>>>((const uint4*)gBf, gBf, rowinfo, csr,
                                                    dinv, b2, Wo, bo,
                                                    nullptr, out, n);
}

// Round 13
// 140.395 us; speedup vs baseline: 1.2682x; 1.1258x over previous
//
#include <hip/hip_runtime.h>

// GCN 2-layer + linear head on MI355X.
// R12 post-mortem: 2-nodes/wave worked (177->158). R13:
//  (a) GEMM: readfirstlane the row index -> SGPR row pointer -> compiler
//      emits scalar s_loads + v_fmac v,s,v (1 instr/FMA, was 2 w/ readlane).
//  (b) agg: FOUR nodes/wave (16 lanes = 2 edge-grps x 8 quads); reduce is
//      one halving round (4 shfl); float4 epilogue.
//  (c) self-loop folded into CSR as an extra edge (k_csr appends own index
//      before x2 padding) -- separate self-term path deleted.

typedef float v2f __attribute__((ext_vector_type(2)));

constexpr int NB_SHIFT = 8;                 // 256 nodes per bucket
constexpr int BUCK_NODES = 1 << NB_SHIFT;
constexpr int CAP = 5120;                   // slab cap (max bucket ~3500 + 512 self + pad)
constexpr int CHUNK = 4096;                 // edges per sort block
constexpr int STPB = 512;
// assumes nbuck <= 512, src < 2^17, padded bucket size <= CAP

// ---- init: slab cursors + dummy bf16 row (replaces hipMemsetAsync) -----
__global__ __launch_bounds__(512) void k_init(int* __restrict__ gcur, int nbuck,
                                              unsigned short* __restrict__ dummyRow) {
    int t = threadIdx.x;
    if (t < nbuck) gcur[t] = 0;
    if (t < 64) dummyRow[t] = 0;
}

// ---- fused: chunk histogram -> slab reserve -> LDS sort -> dense flush -
__global__ __launch_bounds__(STPB) void k_bsort(const int* __restrict__ src,
                                                const int* __restrict__ dst, int E, int nbuck,
                                                int* __restrict__ gcur,
                                                unsigned* __restrict__ packed) {
    __shared__ int shStart[512];
    __shared__ int shCur[512];
    __shared__ int shOff[512];
    __shared__ unsigned stage[CHUNK];
    __shared__ unsigned short sbkt[CHUNK];
    const int tid = threadIdx.x;
    const int base = blockIdx.x * CHUNK;
    const int end = min(base + CHUNK, E);
    // pass A: count buckets in this chunk (LDS atomics)
    shCur[tid] = 0;
    __syncthreads();
    for (int e = base + tid; e < end; e += STPB)
        atomicAdd(&shCur[dst[e] >> NB_SHIFT], 1);
    __syncthreads();
    int v = shCur[tid];
    shStart[tid] = v;
    __syncthreads();
    for (int s = 1; s < 512; s <<= 1) {      // inclusive Hillis-Steele
        int a = (tid >= s) ? shStart[tid - s] : 0;
        __syncthreads();
        shStart[tid] += a;
        __syncthreads();
    }
    int exc = shStart[tid] - v;
    shStart[tid] = exc;
    shCur[tid] = exc;
    // reserve this chunk's span in bucket slabs (one global atomic each)
    if (tid < nbuck) shOff[tid] = tid * CAP + ((v > 0) ? atomicAdd(&gcur[tid], v) : 0);
    __syncthreads();
    // pass B: permute chunk into LDS, bucket-major
    for (int e = base + tid; e < end; e += STPB) {
        int s = src[e];
        int d = dst[e];
        int b = d >> NB_SHIFT;
        int slot = atomicAdd(&shCur[b], 1);
        stage[slot] = ((unsigned)(d & (BUCK_NODES - 1)) << 17) | (unsigned)s;
        sbkt[slot] = (unsigned short)b;
    }
    __syncthreads();
    // pass C: linear flush, same-bucket runs land contiguously
    int cnt = end - base;
    for (int i = tid; i < cnt; i += STPB) {
        int b = sbkt[i];
        packed[shOff[b] + (i - shStart[b])] = stage[i];
    }
}

// ---- per-bucket counting sort by dstLocal -> csr slab; appends SELF edge
//      then pads to x2. rowinfo=(start, paddedCount), dinv ---------------
__global__ __launch_bounds__(512) void k_csr(const unsigned* __restrict__ packed,
                                             const int* __restrict__ gcur, int n,
                                             int* __restrict__ csr, int2* __restrict__ rowinfo,
                                             float* __restrict__ dinv) {
    __shared__ int cnt[BUCK_NODES];
    __shared__ int scn[BUCK_NODES];
    __shared__ int cur[BUCK_NODES];
    const int tid = threadIdx.x;
    const int e0 = blockIdx.x * CAP;
    const int e1 = e0 + gcur[blockIdx.x];     // slab base + size
    if (tid < BUCK_NODES) cnt[tid] = 0;
    __syncthreads();
    for (int e = e0 + tid; e < e1; e += 512)
        atomicAdd(&cnt[packed[e] >> 17], 1);
    __syncthreads();
    int v = (tid < BUCK_NODES) ? cnt[tid] : 0;
    int pad = (v + 2) & ~1;                   // v edges + 1 self, rounded to x2
    if (tid < BUCK_NODES) scn[tid] = pad;
    __syncthreads();
    for (int s = 1; s < BUCK_NODES; s <<= 1) {   // inclusive Hillis-Steele
        int add = (tid >= s && tid < BUCK_NODES) ? scn[tid - s] : 0;
        __syncthreads();
        if (tid < BUCK_NODES) scn[tid] += add;
        __syncthreads();
    }
    int start = 0;
    if (tid < BUCK_NODES) {
        start = e0 + scn[tid] - pad;
        cur[tid] = start;
        int node = blockIdx.x * BUCK_NODES + tid;
        if (node < n) {
            rowinfo[node] = make_int2(start, pad);
            dinv[node] = rsqrtf(1.0f + (float)v);
        }
    }
    __syncthreads();
    for (int e = e0 + tid; e < e1; e += 512) {
        unsigned p = packed[e];
        int pos = atomicAdd(&cur[p >> 17], 1);   // LDS cursor
        csr[pos] = (int)(p & 0x1FFFFu);          // dense slab window, L2-hot
    }
    __syncthreads();
    // append self edge, then dummy-pad (index n = zero bf16 row)
    if (tid < BUCK_NODES) {
        int node = blockIdx.x * BUCK_NODES + tid;
        csr[start + v] = (node < n) ? node : n;
        for (int p = v + 1; p < pad; ++p) csr[start + p] = n;
    }
}

// ---- GEMM: gBf[i][f] = bf16((sum_k A[i][k] * W[k][f]) * dinv[i]) -------
// A-row pointer forced to SGPR via readfirstlane -> scalar s_loads,
// v_fmac v,s,v = 1 VALU instr per FMA.
__global__ __launch_bounds__(256) void k_gemm64bf(const float* __restrict__ A,
                                                  const float* __restrict__ W,
                                                  const float* __restrict__ dinv,
                                                  unsigned short* __restrict__ out,
                                                  int n) {
    const int lane = threadIdx.x & 63;
    const int wave = threadIdx.x >> 6;
    float wcol[64];
#pragma unroll
    for (int k = 0; k < 64; ++k) wcol[k] = W[k * 64 + lane];
    int base = blockIdx.x * 64;
    for (int r = wave; r < 64; r += 4) {
        int row = base + r;
        if (row >= n) break;
        int urow = __builtin_amdgcn_readfirstlane(row);   // SGPR row index
        const float* Ar = A + (size_t)urow * 64;          // uniform -> s_load path
        float acc = 0.0f;
#pragma unroll
        for (int k = 0; k < 64; ++k) acc = fmaf(Ar[k], wcol[k], acc);
        float val = acc * dinv[urow];
        unsigned u = __float_as_uint(val);
        u = (u + 0x7FFFu + ((u >> 16) & 1u)) >> 16;   // RNE to bf16
        out[(size_t)urow * 64 + lane] = (unsigned short)u;
    }
}

__device__ __forceinline__ v2f bf2(unsigned u) {
    v2f r;
    r.x = __uint_as_float(u << 16);
    r.y = __uint_as_float(u & 0xFFFF0000u);
    return r;
}

// ---- Aggregate: FOUR nodes per wave (16 lanes each); bf16 rows ---------
// lane = 16*s + 8*grp + q. Node slot s; grp in {0,1} handles edge e+2r+grp;
// q the 16B row chunk (features 8q..8q+7). Self-loop is already in csr.
// Reduce: 1 halving round (mask 8) -> each lane owns 4 features
// base = 8q + 4*grp; float4 epilogue.
template <bool LAST>
__global__ __launch_bounds__(256) void k_aggregate(
    const uint4* __restrict__ g4,
    const int2* __restrict__ rowinfo, const int* __restrict__ csr,
    const float* __restrict__ dinv, const float* __restrict__ bias,
    const float* __restrict__ Wo, const float* __restrict__ bo,
    float* __restrict__ outRow, float* __restrict__ outHead, int n) {
    int w = (blockIdx.x * blockDim.x + threadIdx.x) >> 6;
    int lane = threadIdx.x & 63;
    const int s = lane >> 4;                  // node slot 0..3
    const int grp = (lane >> 3) & 1;          // 0..1
    const int q = lane & 7;                   // 0..7
    int node = 4 * w + s;
    const bool valid = node < n;
    int2 ri = valid ? rowinfo[node] : make_int2(0, 0);
    const int e = ri.x;
    const int rnds = ri.y >> 1;
    int rm = rnds;
    rm = max(rm, __shfl_xor(rm, 16, 64));
    rm = max(rm, __shfl_xor(rm, 32, 64));     // max over 4 slots
    v2f a0v = {0.f, 0.f}, a1v = {0.f, 0.f}, a2v = {0.f, 0.f}, a3v = {0.f, 0.f};
    int r = 0;
    for (; r + 2 <= rm; r += 2) {             // 16 edge-rows in flight / wave
        int c0 = csr[e + 2 * r + grp];
        int c1 = csr[e + 2 * r + 2 + grp];
        int i0 = (r < rnds) ? c0 : n;
        int i1 = (r + 1 < rnds) ? c1 : n;
        uint4 x0 = g4[(size_t)i0 * 8 + q];
        uint4 x1 = g4[(size_t)i1 * 8 + q];
        a0v += bf2(x0.x); a1v += bf2(x0.y); a2v += bf2(x0.z); a3v += bf2(x0.w);
        a0v += bf2(x1.x); a1v += bf2(x1.y); a2v += bf2(x1.z); a3v += bf2(x1.w);
    }
    if (r < rm) {
        int c0 = csr[e + 2 * r + grp];
        int i0 = (r < rnds) ? c0 : n;
        uint4 x0 = g4[(size_t)i0 * 8 + q];
        a0v += bf2(x0.x); a1v += bf2(x0.y); a2v += bf2(x0.z); a3v += bf2(x0.w);
    }
    // one halving round over grp (mask 8): grp0 ends with feat 8q..8q+3,
    // grp1 with 8q+4..8q+7
    v2f keep0 = grp ? a2v : a0v;
    v2f keep1 = grp ? a3v : a1v;
    v2f send0 = grp ? a0v : a2v;
    v2f send1 = grp ? a1v : a3v;
    keep0.x += __shfl_xor(send0.x, 8, 64);
    keep0.y += __shfl_xor(send0.y, 8, 64);
    keep1.x += __shfl_xor(send1.x, 8, 64);
    keep1.y += __shfl_xor(send1.y, 8, 64);
    const int base = 8 * q + 4 * grp;
    float dv = valid ? dinv[node] : 0.f;
    float4 bb = *(const float4*)&bias[base];
    float4 vv;
    vv.x = fmaxf(fmaf(dv, keep0.x, bb.x), 0.f);
    vv.y = fmaxf(fmaf(dv, keep0.y, bb.y), 0.f);
    vv.z = fmaxf(fmaf(dv, keep1.x, bb.z), 0.f);
    vv.w = fmaxf(fmaf(dv, keep1.y, bb.w), 0.f);
    if constexpr (LAST) {
        float4 ww = *(const float4*)&Wo[base];
        float p = vv.x * ww.x + vv.y * ww.y + vv.z * ww.z + vv.w * ww.w;
#pragma unroll
        for (int m = 1; m <= 8; m <<= 1) p += __shfl_xor(p, m, 64);
        if ((lane & 15) == 0 && valid) outHead[node] = p + bo[0];
    } else {
        if (valid) *(float4*)&outRow[(size_t)node * 64 + base] = vv;
    }
}

extern "C" void kernel_launch(void* const* d_in, const int* in_sizes, int n_in,
                              void* d_out, int out_size, void* d_ws, size_t ws_size,
                              hipStream_t stream) {
    const float* x  = (const float*)d_in[0];
    const int*   ei = (const int*)d_in[1];
    const float* W1 = (const float*)d_in[2];
    const float* b1 = (const float*)d_in[3];
    const float* W2 = (const float*)d_in[4];
    const float* b2 = (const float*)d_in[5];
    const float* Wo = (const float*)d_in[6];
    const float* bo = (const float*)d_in[7];
    float* out = (float*)d_out;

    const int n = in_sizes[0] / 64;
    const int E = in_sizes[1] / 2;
    const int* src = ei;
    const int* dst = ei + E;

    const int nbuck = (n + BUCK_NODES - 1) >> NB_SHIFT;      // 391
    const int nchunks = (E + CHUNK - 1) / CHUNK;             // 306

    char* ws = (char*)d_ws;
    size_t off = 0;
    auto alloc = [&](size_t bytes) -> void* {
        void* p = ws + off;
        off += (bytes + 255) & ~(size_t)255;
        return p;
    };
    const size_t slabBytes = (size_t)nbuck * CAP * 4;        // 8.0 MB
    const size_t hBytes    = (size_t)n * 64 * 4;             // 25.6 MB (fp32 h1)
    const size_t gBytes    = (size_t)(n + 1) * 64 * 2;       // 12.8 MB (bf16 g + dummy)
    float*          dinv    = (float*)alloc((size_t)n * 4);
    int*            gcur    = (int*)alloc((size_t)nbuck * 4);
    int2*           rowinfo = (int2*)alloc((size_t)n * 8);
    int*            csr     = (int*)alloc(slabBytes);
    char*           regionA = (char*)alloc(hBytes > slabBytes ? hBytes : slabBytes);
    unsigned short* gBf     = (unsigned short*)alloc(gBytes);
    unsigned* packed = (unsigned*)regionA;   // dead after k_csr
    float*    bufH   = (float*)regionA;      // h1 (fp32), written from agg1 on

    // ---- init (slab cursors + dummy bf16 row) ----
    k_init<<<1, 512, 0, stream>>>(gcur, nbuck, gBf + (size_t)n * 64);

    // ---- slab counting sort -> dst-sorted csr slabs + rowinfo + dinv ----
    k_bsort<<<nchunks, STPB, 0, stream>>>(src, dst, E, nbuck, gcur, packed);
    k_csr<<<nbuck, 512, 0, stream>>>(packed, gcur, n, csr, rowinfo, dinv);

    const int gemmGrid = (n + 63) / 64;
    const int nodeGrid = (n + 15) / 16;      // 4 nodes/wave, 4 waves/block

    // ---- layer 1 ----
    k_gemm64bf<<<gemmGrid, 256, 0, stream>>>(x, W1, dinv, gBf, n);
    k_aggregate<false><<<nodeGrid, 256, 0, stream>>>((const uint4*)gBf, rowinfo, csr,
                                                     dinv, b1, nullptr, nullptr,
                                                     bufH, nullptr, n);
    // ---- layer 2 (head fused into epilogue) ----
    k_gemm64bf<<<gemmGrid, 256, 0, stream>>>(bufH, W2, dinv, gBf, n);
    k_aggregate<true><<<nodeGrid, 256, 0, stream>>>((const uint4*)gBf, rowinfo, csr,
                                                    dinv, b2, Wo, bo,
                                                    nullptr, out, n);
}